// Round 6
// baseline (2087.750 us; speedup 1.0000x reference)
//
#include <hip/hip_runtime.h>

#define NN 50000
#define NE 150000
#define CAP 32    // bucket capacity; degrees Poisson(3), P(deg>=32) ~ 1e-20
#define NB 782    // grid; <= 4 blocks/CU co-resident (1024 slots >= 782)
#define NT 256
#define NPH 5     // hierarchical barriers
#define NPB 64    // conv2 tile nodes per block

struct __align__(64) PadCtr { int v; int pad[15]; };

// Two-level hierarchical grid barrier.
// Arrivals: block -> group counter (64 groups, <=13 arrivals each, own cache line)
//           group-last -> root counter (64 arrivals).
// Release:  root-last stores 64 per-group flags; leaders poll OWN group flag only
//           (<=13 pollers/line at ~1.7us poll interval -> below line service rate).
__device__ __forceinline__ void hbar(PadCtr* grp, PadCtr* root, PadCtr* rel, int b) {
    __syncthreads();
    if (threadIdx.x == 0) {
        __threadfence();
        int g = b & 63;
        int tgt = ((NB - 1 - g) >> 6) + 1;   // group size (12 or 13)
        int old = __hip_atomic_fetch_add(&grp[g].v, 1, __ATOMIC_ACQ_REL,
                                         __HIP_MEMORY_SCOPE_AGENT);
        if (old == tgt - 1) {                // last in group
            int o2 = __hip_atomic_fetch_add(&root->v, 1, __ATOMIC_ACQ_REL,
                                            __HIP_MEMORY_SCOPE_AGENT);
            if (o2 == 63) {                  // last group overall: release all
                for (int i = 0; i < 64; i++)
                    __hip_atomic_store(&rel[i].v, 1, __ATOMIC_RELEASE,
                                       __HIP_MEMORY_SCOPE_AGENT);
            }
        }
        int spins = 0;
        while (__hip_atomic_load(&rel[g].v, __ATOMIC_ACQUIRE,
                                 __HIP_MEMORY_SCOPE_AGENT) == 0) {
            __builtin_amdgcn_s_sleep(64);    // ~1.7us between polls
            if (++spins > 400000) break;     // hang guard
        }
        __threadfence();
    }
    __syncthreads();
}

__global__ __launch_bounds__(NT, 4) void k_fused(
    const int* __restrict__ src, const int* __restrict__ dst,
    const float* __restrict__ x, const float* __restrict__ ef,
    const float* __restrict__ W1, const float* __restrict__ b1,
    const float* __restrict__ W2, const float* __restrict__ b2,
    const float* __restrict__ W3, const float* __restrict__ b3,
    const float* __restrict__ Wv1, const float* __restrict__ bv1,
    const float* __restrict__ Wv2, const float* __restrict__ bv2,
    const float* __restrict__ Wa1, const float* __restrict__ ba1,
    const float* __restrict__ Wa2, const float* __restrict__ ba2,
    PadCtr* grp, PadCtr* root, PadCtr* rel, PadCtr* done,
    int* cnt_in, int* cnt_out, int2* pbuck, int* obuck,
    float* c, float* h1s, float* t, float* hv_raw, float* ha_raw,
    float* a_acc, float* v, float* out)
{
    __shared__ float tile[NPB * 11];
    __shared__ float din_sh[NPB], w_sh[NPB];
    __shared__ float ts[512];
    __shared__ float gpart[256];
    __shared__ float gs[64];
    __shared__ float sh[256];
    __shared__ int lastFlag;

    int tid = threadIdx.x, b = blockIdx.x;
    int gtid = b * NT + tid;

    // ---- P0: zero accumulators ----
    for (int i = gtid; i < NN; i += NB * NT) { cnt_in[i] = 0; cnt_out[i] = 0; }
    if (gtid < 512)  t[gtid] = 0.f;
    if (gtid < 2048) { hv_raw[gtid] = 0.f; ha_raw[gtid] = 0.f; }
    if (gtid < 1024) a_acc[gtid] = 0.f;
    hbar(grp + 0 * 64, root + 0, rel + 0 * 64, b);

    // ---- P1: degree count + bucket scatter ----
    if (gtid < NE) {
        int e = gtid;
        int s = src[e], d = dst[e];
        int si = atomicAdd(&cnt_in[d], 1) & (CAP - 1);
        pbuck[(size_t)d * CAP + si] = make_int2(e, s);
        int so = atomicAdd(&cnt_out[s], 1) & (CAP - 1);
        obuck[(size_t)s * CAP + so] = d;
    }
    hbar(grp + 1 * 64, root + 1, rel + 1 * 64, b);

    // ---- P2: conv1 gather (4 lanes/node, on-the-fly scales) + c + matvec/relu ----
    {
        int n = gtid >> 2, sub = gtid & 3;
        if (n < NN) {
            int ci = cnt_in[n], co = cnt_out[n];
            float din  = rsqrtf((float)(ci + 1));
            float dout = rsqrtf((float)(co + 1));
            float a0 = 0.f, a1 = 0.f, a2 = 0.f, a3 = 0.f;
            const int2* pb = pbuck + (size_t)n * CAP;
            for (int i = sub; i < ci; i += 4) {
                int2 p = pb[i];
                float os = rsqrtf((float)(cnt_out[p.y] + 1));
                float4 u = ((const float4*)x)[p.y];
                a0 = fmaf(u.x, os, a0); a1 = fmaf(u.y, os, a1);
                a2 = fmaf(u.z, os, a2); a3 = fmaf(u.w, os, a3);
            }
            float cacc = 0.f;
            const int* ob = obuck + (size_t)n * CAP;
            for (int i = sub; i < co; i += 4) cacc += rsqrtf((float)(cnt_in[ob[i]] + 1));
            #pragma unroll
            for (int m = 1; m < 4; m <<= 1) {
                a0 += __shfl_xor(a0, m); a1 += __shfl_xor(a1, m);
                a2 += __shfl_xor(a2, m); a3 += __shfl_xor(a3, m);
                cacc += __shfl_xor(cacc, m);
            }
            float4 sv = ((const float4*)x)[n];
            a0 = fmaf(sv.x, dout, a0); a1 = fmaf(sv.y, dout, a1);
            a2 = fmaf(sv.z, dout, a2); a3 = fmaf(sv.w, dout, a3);
            if (sub == 0) c[n] = cacc + din;
            #pragma unroll
            for (int jj = 0; jj < 3; jj++) {
                int j = sub + 4 * jj;
                if (j < 11) {
                    float y = a0 * W1[0 * 11 + j] + a1 * W1[1 * 11 + j] +
                              a2 * W1[2 * 11 + j] + a3 * W1[3 * 11 + j];
                    y = fmaxf(fmaf(y, din, b1[j]), 0.f);
                    h1s[(size_t)n * 11 + j] = y * dout;
                }
            }
        }
    }
    hbar(grp + 2 * 64, root + 2, rel + 2 * 64, b);

    // ---- P3: conv2 aggregation (bucket gather -> LDS) + matvec/relu + t reduce ----
    {
        int n0 = b * NPB;   // NB*NPB = 50048 covers NN
        for (int idx = tid; idx < NPB * 11; idx += NT) {
            int q = idx / 11, j = idx - q * 11;
            int n = n0 + q;
            float acc = 0.f;
            if (n < NN) {
                int ci = cnt_in[n];
                const int2* pb = pbuck + (size_t)n * CAP;
                for (int i = 0; i < ci; i++) {
                    int2 p = pb[i];
                    acc = fmaf(h1s[(size_t)p.y * 11 + j], ef[(size_t)p.x * 11 + j], acc);
                }
            }
            tile[idx] = acc;
        }
        if (tid < NPB) {
            int node = n0 + tid;
            if (node < NN) {
                din_sh[tid] = rsqrtf((float)(cnt_in[node] + 1));
                w_sh[tid]   = c[node] * rsqrtf((float)(cnt_out[node] + 1)) * (1.0f / NN);
            } else { din_sh[tid] = 0.f; w_sh[tid] = 0.f; }
        }
        __syncthreads();
        float w0[11], w1[11];
        #pragma unroll
        for (int j = 0; j < 11; j++) { w0[j] = W2[j * 512 + tid]; w1[j] = W2[j * 512 + tid + 256]; }
        float bias0 = b2[tid], bias1 = b2[tid + 256];
        float acc0 = 0.f, acc1 = 0.f;
        for (int i = 0; i < NPB; i++) {
            float d0 = 0.f, d1 = 0.f;
            #pragma unroll
            for (int j = 0; j < 11; j++) {
                float tv = tile[i * 11 + j];
                d0 = fmaf(tv, w0[j], d0); d1 = fmaf(tv, w1[j], d1);
            }
            float y0 = fmaxf(fmaf(d0, din_sh[i], bias0), 0.f);
            float y1 = fmaxf(fmaf(d1, din_sh[i], bias1), 0.f);
            acc0 = fmaf(w_sh[i], y0, acc0);
            acc1 = fmaf(w_sh[i], y1, acc1);
        }
        atomicAdd(&t[tid], acc0);
        atomicAdd(&t[tid + 256], acc1);
        __syncthreads();
    }
    hbar(grp + 3 * 64, root + 3, rel + 3 * 64, b);

    // ---- P4: g-slice recompute + heads layer-1 partials (blocks 0..255) ----
    if (b < 256) {
        int oc = b >> 4, kc = b & 15;
        int k0 = kc * 64;
        ts[tid] = t[tid];
        ts[tid + 256] = t[tid + 256];
        __syncthreads();
        {
            int i = tid & 63, kp = tid >> 6;
            float p = 0.f;
            int kb = kp * 128;
            #pragma unroll 8
            for (int k = 0; k < 128; k++)
                p = fmaf(ts[kb + k], W3[(size_t)(kb + k) * 1024 + k0 + i], p);
            gpart[tid] = p;
            __syncthreads();
            if (tid < 64)
                gs[tid] = b3[k0 + tid] + gpart[tid] + gpart[64 + tid] +
                          gpart[128 + tid] + gpart[192 + tid];
            __syncthreads();
        }
        int idx = oc * 256 + tid;  // 0..4095
        const float* W; float* outp; int o;
        if (idx < 2048) { W = Wv1; outp = hv_raw; o = idx; }
        else            { W = Wa1; outp = ha_raw; o = idx - 2048; }
        float acc = 0.f;
        #pragma unroll 8
        for (int k = 0; k < 64; k++)
            acc = fmaf(gs[k], W[(size_t)(k0 + k) * 2048 + o], acc);
        atomicAdd(&outp[o], acc);
    }
    hbar(grp + 4 * 64, root + 4, rel + 4 * 64, b);

    // ---- P5: heads layer-2 (a partials blocks 0..127, v block 128) ----
    if (b < 128) {
        int oc = b >> 5, kc = b & 31;
        int k0 = kc * 64;
        if (tid < 64) sh[tid] = fmaxf(ha_raw[k0 + tid] + ba1[k0 + tid], 0.f);
        __syncthreads();
        int o = oc * 256 + tid;
        if (o < 1000) {
            float acc = 0.f;
            #pragma unroll 8
            for (int k = 0; k < 64; k++)
                acc = fmaf(sh[k], Wa2[(size_t)(k0 + k) * 1000 + o], acc);
            atomicAdd(&a_acc[o], acc);
        }
        __syncthreads();
    } else if (b == 128) {
        float acc = 0.f;
        for (int k = tid; k < 2048; k += 256)
            acc = fmaf(fmaxf(hv_raw[k] + bv1[k], 0.f), Wv2[k], acc);
        sh[tid] = acc;
        __syncthreads();
        for (int s2 = 128; s2 >= 1; s2 >>= 1) {
            if (tid < s2) sh[tid] += sh[tid + s2];
            __syncthreads();
        }
        if (tid == 0) *v = sh[0] + bv2[0];
        __syncthreads();
    }

    // ---- final: exit-style; last arriving block computes out ----
    __syncthreads();
    if (tid == 0) {
        __threadfence();
        int old = __hip_atomic_fetch_add(&done->v, 1, __ATOMIC_ACQ_REL,
                                         __HIP_MEMORY_SCOPE_AGENT);
        lastFlag = (old == NB - 1) ? 1 : 0;
    }
    __syncthreads();
    if (!lastFlag) return;
    __threadfence();
    float ai[4];
    float lsum = 0.f;
    #pragma unroll
    for (int k = 0; k < 4; k++) {
        int idx = tid + k * 256;
        float val = (idx < 1000) ? a_acc[idx] + ba2[idx] : 0.f;
        ai[k] = val;
        lsum += val;
    }
    __syncthreads();
    sh[tid] = lsum;
    __syncthreads();
    for (int s2 = 128; s2 >= 1; s2 >>= 1) {
        if (tid < s2) sh[tid] += sh[tid + s2];
        __syncthreads();
    }
    float amean = sh[0] * (1.0f / 1000.0f);
    float vv = *v;
    #pragma unroll
    for (int k = 0; k < 4; k++) {
        int idx = tid + k * 256;
        if (idx < 1000) out[idx] = vv + ai[k] - amean;
    }
}

extern "C" void kernel_launch(void* const* d_in, const int* in_sizes, int n_in,
                              void* d_out, int out_size, void* d_ws, size_t ws_size,
                              hipStream_t stream) {
    const float* x   = (const float*)d_in[0];
    const float* ef  = (const float*)d_in[1];
    const float* W1  = (const float*)d_in[2];
    const float* b1  = (const float*)d_in[3];
    const float* W2  = (const float*)d_in[4];
    const float* b2  = (const float*)d_in[5];
    const float* W3  = (const float*)d_in[6];
    const float* b3  = (const float*)d_in[7];
    const float* Wv1 = (const float*)d_in[8];
    const float* bv1 = (const float*)d_in[9];
    const float* Wv2 = (const float*)d_in[10];
    const float* bv2 = (const float*)d_in[11];
    const float* Wa1 = (const float*)d_in[12];
    const float* ba1 = (const float*)d_in[13];
    const float* Wa2 = (const float*)d_in[14];
    const float* ba2 = (const float*)d_in[15];
    const int*   src = (const int*)d_in[16];
    const int*   dst = (const int*)d_in[17];
    float* out = (float*)d_out;

    char* ws = (char*)d_ws;
    size_t off = 0;
    auto alloc = [&](size_t bytes) -> void* {
        void* p = ws + off;
        off = (off + bytes + 255) & ~(size_t)255;
        return p;
    };
    // --- zeroed region: barrier structures only (~42KB) ---
    PadCtr* grp  = (PadCtr*)alloc(NPH * 64 * sizeof(PadCtr));
    PadCtr* root = (PadCtr*)alloc(NPH * sizeof(PadCtr));
    PadCtr* rel  = (PadCtr*)alloc(NPH * 64 * sizeof(PadCtr));
    PadCtr* done = (PadCtr*)alloc(sizeof(PadCtr));
    size_t zero_bytes = off;
    // --- non-zeroed scratch (accumulators zeroed in-kernel P0) ---
    int*   cnt_in  = (int*)  alloc(NN * 4);
    int*   cnt_out = (int*)  alloc(NN * 4);
    int2*  pbuck   = (int2*) alloc((size_t)NN * CAP * 8);
    int*   obuck   = (int*)  alloc((size_t)NN * CAP * 4);
    float* c       = (float*)alloc(NN * 4);
    float* h1s     = (float*)alloc((size_t)NN * 11 * 4);
    float* t       = (float*)alloc(512 * 4);
    float* hv_raw  = (float*)alloc(2048 * 4);
    float* ha_raw  = (float*)alloc(2048 * 4);
    float* a_acc   = (float*)alloc(1024 * 4);
    float* v       = (float*)alloc(256);

    hipMemsetAsync(d_ws, 0, zero_bytes, stream);

    k_fused<<<NB, NT, 0, stream>>>(src, dst, x, ef, W1, b1, W2, b2, W3, b3,
                                   Wv1, bv1, Wv2, bv2, Wa1, ba1, Wa2, ba2,
                                   grp, root, rel, done,
                                   cnt_in, cnt_out, pbuck, obuck,
                                   c, h1s, t, hv_raw, ha_raw, a_acc, v, out);
}

// Round 7
// 533.147 us; speedup vs baseline: 3.9159x; 3.9159x over previous
//
#include <hip/hip_runtime.h>

#define NN 50000
#define NE 150000
#define CAP 32    // bucket capacity; degrees Poisson(3), P(deg>=32) ~ 1e-20
#define NB 768    // cooperative grid: 3 blocks/CU guaranteed co-resident (launch_bounds 4/CU cap)
#define NT 256
#define NPH 7
#define NPB 64
#define NVB2 782  // ceil(NN/NPB)

struct __align__(64) PadCtr { int v; int pad[15]; };

struct KParams {
    const int *src, *dst;
    const float *x, *ef, *W1, *b1, *W2, *b2, *W3, *b3;
    const float *Wv1, *bv1, *Wv2, *bv2, *Wa1, *ba1, *Wa2, *ba2;
    PadCtr *grp, *root, *rel;
    int *cnt_in, *cnt_out; int2 *pbuck; int *obuck;
    float *din_arr; float4 *dsx4;
    float *c, *h1s, *t, *hv_raw, *ha_raw, *a_acc, *v, *out;
};

// Hierarchical grid barrier. REQUIRES co-residency (cooperative launch).
// Arrivals: 64 padded group counters (12 RMWs each, parallel lines) -> root (64 RMWs).
// Release: root-last fans out 64 per-group flags; leaders poll OWN flag, RELAXED + fence.
__device__ __forceinline__ void hbar(PadCtr* grp, PadCtr* root, PadCtr* rel, int b) {
    __syncthreads();
    if (threadIdx.x == 0) {
        __threadfence();
        int g = b & 63;   // 768/64 = 12 blocks per group exactly
        int old = __hip_atomic_fetch_add(&grp[g].v, 1, __ATOMIC_ACQ_REL,
                                         __HIP_MEMORY_SCOPE_AGENT);
        if (old == (NB / 64) - 1) {
            int o2 = __hip_atomic_fetch_add(&root->v, 1, __ATOMIC_ACQ_REL,
                                            __HIP_MEMORY_SCOPE_AGENT);
            if (o2 == 63) {
                __threadfence();
                for (int i = 0; i < 64; i++)
                    __hip_atomic_store(&rel[i].v, 1, __ATOMIC_RELAXED,
                                       __HIP_MEMORY_SCOPE_AGENT);
            }
        }
        int spins = 0;
        while (__hip_atomic_load(&rel[g].v, __ATOMIC_RELAXED,
                                 __HIP_MEMORY_SCOPE_AGENT) == 0) {
            __builtin_amdgcn_s_sleep(16);       // ~0.4us between polls
            if (++spins > 3000000) break;       // visible-failure guard (~1.2s)
        }
        __threadfence();
    }
    __syncthreads();
}

__global__ __launch_bounds__(NT, 4) void k_fused(KParams p)
{
    __shared__ float smem[832];
    int tid = threadIdx.x, b = blockIdx.x;
    int gtid = b * NT + tid;

    // ---- P0: zero accumulators ----
    for (int i = gtid; i < NN; i += NB * NT) { p.cnt_in[i] = 0; p.cnt_out[i] = 0; }
    if (gtid < 512)  p.t[gtid] = 0.f;
    if (gtid < 2048) { p.hv_raw[gtid] = 0.f; p.ha_raw[gtid] = 0.f; }
    if (gtid < 1024) p.a_acc[gtid] = 0.f;
    hbar(p.grp + 0 * 64, p.root + 0, p.rel + 0 * 64, b);

    // ---- P1: degree count + bucket scatter ----
    for (int e = gtid; e < NE; e += NB * NT) {
        int s = p.src[e], d = p.dst[e];
        int si = atomicAdd(&p.cnt_in[d], 1) & (CAP - 1);
        p.pbuck[(size_t)d * CAP + si] = make_int2(e, s);
        int so = atomicAdd(&p.cnt_out[s], 1) & (CAP - 1);
        p.obuck[(size_t)s * CAP + so] = d;
    }
    hbar(p.grp + 1 * 64, p.root + 1, p.rel + 1 * 64, b);

    // ---- P2: node precompute: din table + dout-prescaled features ----
    for (int n = gtid; n < NN; n += NB * NT) {
        p.din_arr[n] = rsqrtf((float)(p.cnt_in[n] + 1));
        float dout = rsqrtf((float)(p.cnt_out[n] + 1));
        float4 xv = ((const float4*)p.x)[n];
        xv.x *= dout; xv.y *= dout; xv.z *= dout; xv.w *= dout;
        p.dsx4[n] = xv;
    }
    hbar(p.grp + 2 * 64, p.root + 2, p.rel + 2 * 64, b);

    // ---- P3: conv1 gather (4 lanes/node) + c gather + 4->11 matvec/relu ----
    for (int u = gtid; u < NN * 4; u += NB * NT) {
        int n = u >> 2, sub = u & 3;
        int ci = p.cnt_in[n], co = p.cnt_out[n];
        float din  = rsqrtf((float)(ci + 1));
        float dout = rsqrtf((float)(co + 1));
        float a0 = 0.f, a1 = 0.f, a2 = 0.f, a3 = 0.f;
        const int2* pb = p.pbuck + (size_t)n * CAP;
        for (int i = sub; i < ci; i += 4) {
            int2 pr = pb[i];
            float4 u4 = p.dsx4[pr.y];
            a0 += u4.x; a1 += u4.y; a2 += u4.z; a3 += u4.w;
        }
        float cacc = 0.f;
        const int* ob = p.obuck + (size_t)n * CAP;
        for (int i = sub; i < co; i += 4) cacc += p.din_arr[ob[i]];
        #pragma unroll
        for (int m = 1; m < 4; m <<= 1) {
            a0 += __shfl_xor(a0, m); a1 += __shfl_xor(a1, m);
            a2 += __shfl_xor(a2, m); a3 += __shfl_xor(a3, m);
            cacc += __shfl_xor(cacc, m);
        }
        float4 sv = p.dsx4[n];               // self-loop (already dout-scaled)
        a0 += sv.x; a1 += sv.y; a2 += sv.z; a3 += sv.w;
        if (sub == 0) p.c[n] = cacc + din;
        #pragma unroll
        for (int jj = 0; jj < 3; jj++) {
            int j = sub + 4 * jj;
            if (j < 11) {
                float y = a0 * p.W1[0 * 11 + j] + a1 * p.W1[1 * 11 + j] +
                          a2 * p.W1[2 * 11 + j] + a3 * p.W1[3 * 11 + j];
                y = fmaxf(fmaf(y, din, p.b1[j]), 0.f);
                p.h1s[(size_t)n * 11 + j] = y * dout;
            }
        }
    }
    hbar(p.grp + 3 * 64, p.root + 3, p.rel + 3 * 64, b);

    // ---- P4: conv2 aggregation (bucket gather -> LDS) + matvec/relu + t reduce ----
    {
        float* tile   = smem;         // 704
        float* din_sh = smem + 704;   // 64
        float* w_sh   = smem + 768;   // 64
        float w0[11], w1[11];
        #pragma unroll
        for (int j = 0; j < 11; j++) {
            w0[j] = p.W2[j * 512 + tid];
            w1[j] = p.W2[j * 512 + tid + 256];
        }
        float bias0 = p.b2[tid], bias1 = p.b2[tid + 256];
        float acc0 = 0.f, acc1 = 0.f;
        for (int vb = b; vb < NVB2; vb += NB) {
            int n0 = vb * NPB;
            __syncthreads();
            for (int idx = tid; idx < NPB * 11; idx += NT) {
                int q = idx / 11, j = idx - q * 11;
                int n = n0 + q;
                float acc = 0.f;
                if (n < NN) {
                    int ci = p.cnt_in[n];
                    const int2* pb = p.pbuck + (size_t)n * CAP;
                    for (int i = 0; i < ci; i++) {
                        int2 pr = pb[i];
                        acc = fmaf(p.h1s[(size_t)pr.y * 11 + j],
                                   p.ef[(size_t)pr.x * 11 + j], acc);
                    }
                }
                tile[idx] = acc;
            }
            if (tid < NPB) {
                int node = n0 + tid;
                if (node < NN) {
                    din_sh[tid] = p.din_arr[node];
                    w_sh[tid]   = p.c[node] *
                                  rsqrtf((float)(p.cnt_out[node] + 1)) * (1.0f / NN);
                } else { din_sh[tid] = 0.f; w_sh[tid] = 0.f; }
            }
            __syncthreads();
            for (int i = 0; i < NPB; i++) {
                float d0 = 0.f, d1 = 0.f;
                #pragma unroll
                for (int j = 0; j < 11; j++) {
                    float tv = tile[i * 11 + j];
                    d0 = fmaf(tv, w0[j], d0); d1 = fmaf(tv, w1[j], d1);
                }
                float y0 = fmaxf(fmaf(d0, din_sh[i], bias0), 0.f);
                float y1 = fmaxf(fmaf(d1, din_sh[i], bias1), 0.f);
                acc0 = fmaf(w_sh[i], y0, acc0);
                acc1 = fmaf(w_sh[i], y1, acc1);
            }
        }
        atomicAdd(&p.t[tid], acc0);
        atomicAdd(&p.t[tid + 256], acc1);
    }
    hbar(p.grp + 4 * 64, p.root + 4, p.rel + 4 * 64, b);

    // ---- P5: g-slice + heads layer-1 (64 virtual blocks: kc 0..15 x oc' 0..3) ----
    if (b < 64) {
        float* ts    = smem;          // 512
        float* gpart = smem + 512;    // 256
        float* gs    = smem + 768;    // 64
        int kc = b >> 2, ocq = b & 3;
        int k0 = kc * 64;
        ts[tid] = p.t[tid];
        ts[tid + 256] = p.t[tid + 256];
        __syncthreads();
        {
            int i = tid & 63, kp2 = tid >> 6;
            float pp = 0.f;
            int kb = kp2 * 128;
            #pragma unroll 8
            for (int k = 0; k < 128; k++)
                pp = fmaf(ts[kb + k], p.W3[(size_t)(kb + k) * 1024 + k0 + i], pp);
            gpart[tid] = pp;
            __syncthreads();
            if (tid < 64)
                gs[tid] = p.b3[k0 + tid] + gpart[tid] + gpart[64 + tid] +
                          gpart[128 + tid] + gpart[192 + tid];
            __syncthreads();
        }
        #pragma unroll
        for (int rep = 0; rep < 4; rep++) {
            int idx = ocq * 1024 + rep * 256 + tid;   // 0..4095
            const float* W; float* outp; int o;
            if (idx < 2048) { W = p.Wv1; outp = p.hv_raw; o = idx; }
            else            { W = p.Wa1; outp = p.ha_raw; o = idx - 2048; }
            float acc = 0.f;
            #pragma unroll 8
            for (int k = 0; k < 64; k++)
                acc = fmaf(gs[k], W[(size_t)(k0 + k) * 2048 + o], acc);
            atomicAdd(&outp[o], acc);
        }
    }
    hbar(p.grp + 5 * 64, p.root + 5, p.rel + 5 * 64, b);

    // ---- P6: heads layer-2 (a partials vb 0..127; v head vb 128) ----
    if (b < 128) {
        float* sh = smem;
        int oc = b >> 5, kc = b & 31;
        int k0 = kc * 64;
        if (tid < 64) sh[tid] = fmaxf(p.ha_raw[k0 + tid] + p.ba1[k0 + tid], 0.f);
        __syncthreads();
        int o = oc * 256 + tid;
        if (o < 1000) {
            float acc = 0.f;
            #pragma unroll 8
            for (int k = 0; k < 64; k++)
                acc = fmaf(sh[k], p.Wa2[(size_t)(k0 + k) * 1000 + o], acc);
            atomicAdd(&p.a_acc[o], acc);
        }
    } else if (b == 128) {
        float* sh = smem;
        float acc = 0.f;
        for (int k = tid; k < 2048; k += 256)
            acc = fmaf(fmaxf(p.hv_raw[k] + p.bv1[k], 0.f), p.Wv2[k], acc);
        sh[tid] = acc;
        __syncthreads();
        for (int s2 = 128; s2 >= 1; s2 >>= 1) {
            if (tid < s2) sh[tid] += sh[tid + s2];
            __syncthreads();
        }
        if (tid == 0) *p.v = sh[0] + p.bv2[0];
    }
    hbar(p.grp + 6 * 64, p.root + 6, p.rel + 6 * 64, b);

    // ---- P7: final (block 0 only): out = v + a - mean(a) ----
    if (b != 0) return;
    {
        float* sh = smem;
        float ai[4];
        float lsum = 0.f;
        #pragma unroll
        for (int k = 0; k < 4; k++) {
            int idx = tid + k * 256;
            float val = (idx < 1000) ? p.a_acc[idx] + p.ba2[idx] : 0.f;
            ai[k] = val;
            lsum += val;
        }
        __syncthreads();
        sh[tid] = lsum;
        __syncthreads();
        for (int s2 = 128; s2 >= 1; s2 >>= 1) {
            if (tid < s2) sh[tid] += sh[tid + s2];
            __syncthreads();
        }
        float amean = sh[0] * (1.0f / 1000.0f);
        float vv = *p.v;
        #pragma unroll
        for (int k = 0; k < 4; k++) {
            int idx = tid + k * 256;
            if (idx < 1000) p.out[idx] = vv + ai[k] - amean;
        }
    }
}

extern "C" void kernel_launch(void* const* d_in, const int* in_sizes, int n_in,
                              void* d_out, int out_size, void* d_ws, size_t ws_size,
                              hipStream_t stream) {
    char* ws = (char*)d_ws;
    size_t off = 0;
    auto alloc = [&](size_t bytes) -> void* {
        void* p = ws + off;
        off = (off + bytes + 255) & ~(size_t)255;
        return p;
    };
    // --- zeroed region: barrier structures only (~58KB) ---
    PadCtr* grp  = (PadCtr*)alloc(NPH * 64 * sizeof(PadCtr));
    PadCtr* root = (PadCtr*)alloc(NPH * sizeof(PadCtr));
    PadCtr* rel  = (PadCtr*)alloc(NPH * 64 * sizeof(PadCtr));
    size_t zero_bytes = off;
    // --- non-zeroed scratch (accumulators zeroed in-kernel P0) ---
    int*   cnt_in  = (int*)  alloc(NN * 4);
    int*   cnt_out = (int*)  alloc(NN * 4);
    int2*  pbuck   = (int2*) alloc((size_t)NN * CAP * 8);
    int*   obuck   = (int*)  alloc((size_t)NN * CAP * 4);
    float* din_arr = (float*)alloc(NN * 4);
    float4* dsx4   = (float4*)alloc((size_t)NN * 16);
    float* c       = (float*)alloc(NN * 4);
    float* h1s     = (float*)alloc((size_t)NN * 11 * 4);
    float* t       = (float*)alloc(512 * 4);
    float* hv_raw  = (float*)alloc(2048 * 4);
    float* ha_raw  = (float*)alloc(2048 * 4);
    float* a_acc   = (float*)alloc(1024 * 4);
    float* v       = (float*)alloc(256);

    KParams kp;
    kp.src = (const int*)d_in[16];  kp.dst = (const int*)d_in[17];
    kp.x   = (const float*)d_in[0]; kp.ef  = (const float*)d_in[1];
    kp.W1  = (const float*)d_in[2]; kp.b1  = (const float*)d_in[3];
    kp.W2  = (const float*)d_in[4]; kp.b2  = (const float*)d_in[5];
    kp.W3  = (const float*)d_in[6]; kp.b3  = (const float*)d_in[7];
    kp.Wv1 = (const float*)d_in[8]; kp.bv1 = (const float*)d_in[9];
    kp.Wv2 = (const float*)d_in[10]; kp.bv2 = (const float*)d_in[11];
    kp.Wa1 = (const float*)d_in[12]; kp.ba1 = (const float*)d_in[13];
    kp.Wa2 = (const float*)d_in[14]; kp.ba2 = (const float*)d_in[15];
    kp.grp = grp; kp.root = root; kp.rel = rel;
    kp.cnt_in = cnt_in; kp.cnt_out = cnt_out; kp.pbuck = pbuck; kp.obuck = obuck;
    kp.din_arr = din_arr; kp.dsx4 = dsx4;
    kp.c = c; kp.h1s = h1s; kp.t = t; kp.hv_raw = hv_raw; kp.ha_raw = ha_raw;
    kp.a_acc = a_acc; kp.v = v; kp.out = (float*)d_out;

    hipMemsetAsync(d_ws, 0, zero_bytes, stream);

    void* args[] = { &kp };
    hipLaunchCooperativeKernel((const void*)k_fused, dim3(NB), dim3(NT),
                               args, 0, stream);
}

// Round 8
// 219.221 us; speedup vs baseline: 9.5235x; 2.4320x over previous
//
#include <hip/hip_runtime.h>

#define NN 50000
#define NE 150000
#define CAP 32   // max bucket slots; degrees are Poisson(3), P(deg>=32) ~ 1e-20

// ---------- K1: fused degree-count + bucket scatter ----------
__global__ __launch_bounds__(256) void k_scat(const int* __restrict__ src,
                                              const int* __restrict__ dst,
                                              int* __restrict__ cnt_in,
                                              int* __restrict__ cnt_out,
                                              int2* __restrict__ pbuck,
                                              int* __restrict__ obuck) {
    int e = blockIdx.x * 256 + threadIdx.x;
    if (e >= NE) return;
    int s = src[e], d = dst[e];
    int si = atomicAdd(&cnt_in[d], 1) & (CAP - 1);
    pbuck[(size_t)d * CAP + si] = make_int2(e, s);
    int so = atomicAdd(&cnt_out[s], 1) & (CAP - 1);
    obuck[(size_t)s * CAP + so] = d;
}

// ---------- K2: per-node precompute: din table + pre-scaled features ----------
__global__ __launch_bounds__(256) void k_node(const float* __restrict__ x,
                                              const int* __restrict__ cnt_in,
                                              const int* __restrict__ cnt_out,
                                              float* __restrict__ din_arr,
                                              float4* __restrict__ dsx4) {
    int n = blockIdx.x * 256 + threadIdx.x;
    if (n >= NN) return;
    din_arr[n] = rsqrtf((float)(cnt_in[n] + 1));
    float dout = rsqrtf((float)(cnt_out[n] + 1));
    float4 xv = ((const float4*)x)[n];
    xv.x *= dout; xv.y *= dout; xv.z *= dout; xv.w *= dout;
    dsx4[n] = xv;
}

// ---------- K3: conv1 gather (4 lanes/node) + c gather + 4->11 matvec/relu ----------
__global__ __launch_bounds__(256) void k_conv1c(const int* __restrict__ cnt_in,
                                                const int* __restrict__ cnt_out,
                                                const int2* __restrict__ pbuck,
                                                const int* __restrict__ obuck,
                                                const float* __restrict__ din_arr,
                                                const float4* __restrict__ dsx4,
                                                const float* __restrict__ W1,
                                                const float* __restrict__ b1,
                                                float* __restrict__ h1s,
                                                float* __restrict__ c) {
    int tid = threadIdx.x;
    int n = blockIdx.x * 64 + (tid >> 2);
    int sub = tid & 3;
    if (n >= NN) return;
    int ci = cnt_in[n], co = cnt_out[n];
    float din  = rsqrtf((float)(ci + 1));
    float dout = rsqrtf((float)(co + 1));
    float a0 = 0.f, a1 = 0.f, a2 = 0.f, a3 = 0.f;
    const int2* pb = pbuck + (size_t)n * CAP;
    for (int i = sub; i < ci; i += 4) {
        int2 p = pb[i];                  // (e, s); only s needed here
        float4 u = dsx4[p.y];
        a0 += u.x; a1 += u.y; a2 += u.z; a3 += u.w;
    }
    float cacc = 0.f;
    const int* ob = obuck + (size_t)n * CAP;
    for (int i = sub; i < co; i += 4) cacc += din_arr[ob[i]];
    // reduce across the 4-lane group
    #pragma unroll
    for (int m = 1; m < 4; m <<= 1) {
        a0 += __shfl_xor(a0, m); a1 += __shfl_xor(a1, m);
        a2 += __shfl_xor(a2, m); a3 += __shfl_xor(a3, m);
        cacc += __shfl_xor(cacc, m);
    }
    float4 sv = dsx4[n];                 // self-loop term (already dout-scaled)
    a0 += sv.x; a1 += sv.y; a2 += sv.z; a3 += sv.w;
    if (sub == 0) c[n] = cacc + din;     // self-loop contributes din
    #pragma unroll
    for (int jj = 0; jj < 3; jj++) {
        int j = sub + 4 * jj;
        if (j < 11) {
            float y = a0 * W1[0 * 11 + j] + a1 * W1[1 * 11 + j] +
                      a2 * W1[2 * 11 + j] + a3 * W1[3 * 11 + j];
            y = fmaxf(fmaf(y, din, b1[j]), 0.f);
            h1s[(size_t)n * 11 + j] = y * dout;
        }
    }
}

// ---------- K4: conv2 aggregation via pair-bucket gather (self loops ef=0 -> skip) ----------
__global__ __launch_bounds__(256) void k_agg2(const int* __restrict__ cnt_in,
                                              const int2* __restrict__ pbuck,
                                              const float* __restrict__ h1s,
                                              const float* __restrict__ ef,
                                              float* __restrict__ agg2) {
    int tid = threadIdx.x;
    if (tid >= 253) return;
    int q = tid / 11;
    int n = blockIdx.x * 23 + q;
    int j = tid - q * 11;
    if (n >= NN) return;
    int ci = cnt_in[n];
    const int2* pb = pbuck + (size_t)n * CAP;
    float acc = 0.f;
    for (int i = 0; i < ci; i++) {
        int2 p = pb[i];                  // (e, s)
        acc = fmaf(h1s[(size_t)p.y * 11 + j], ef[(size_t)p.x * 11 + j], acc);
    }
    agg2[(size_t)n * 11 + j] = acc;
}

// ---------- K5: conv2 matvec+relu fused with weighted mean-reduction into t[512] ----------
#define NPB 64
__global__ __launch_bounds__(512) void k_conv2_reduce(const float* __restrict__ agg2,
                                                      const float* __restrict__ W2,
                                                      const float* __restrict__ b2,
                                                      const float* __restrict__ c,
                                                      const int* __restrict__ cnt_out,
                                                      const int* __restrict__ cnt_in,
                                                      float* __restrict__ t) {
    __shared__ float tile[NPB * 11];
    __shared__ float din_sh[NPB], w_sh[NPB];
    int n0 = blockIdx.x * NPB;
    int tid = threadIdx.x;
    for (int i = tid; i < NPB * 11; i += 512) {
        int gi = n0 * 11 + i;
        tile[i] = (gi < NN * 11) ? agg2[gi] : 0.f;
    }
    if (tid < NPB) {
        int node = n0 + tid;
        if (node < NN) {
            din_sh[tid] = rsqrtf((float)(cnt_in[node] + 1));
            w_sh[tid]   = c[node] * rsqrtf((float)(cnt_out[node] + 1)) * (1.0f / NN);
        } else { din_sh[tid] = 0.f; w_sh[tid] = 0.f; }
    }
    __syncthreads();
    float w[11];
    #pragma unroll
    for (int j = 0; j < 11; j++) w[j] = W2[j * 512 + tid];
    float bias = b2[tid];
    float acc = 0.f;
    for (int i = 0; i < NPB; i++) {
        float dot = 0.f;
        #pragma unroll
        for (int j = 0; j < 11; j++) dot = fmaf(tile[i * 11 + j], w[j], dot);
        float y = fmaxf(fmaf(dot, din_sh[i], bias), 0.f);
        acc = fmaf(w_sh[i], y, acc);
    }
    atomicAdd(&t[tid], acc);
}

// ---------- K6: g = t @ W3 + b3  (512x1024 matvec, k-split 16 ways) ----------
__global__ __launch_bounds__(256) void k_g(const float* __restrict__ t,
                                           const float* __restrict__ W3,
                                           const float* __restrict__ b3,
                                           float* __restrict__ g) {
    int b = blockIdx.x;          // 64 = 4 oc x 16 kc
    int oc = b & 3, kc = b >> 2;
    int o = oc * 256 + threadIdx.x;
    int k0 = kc * 32;
    __shared__ float ts[32];
    if (threadIdx.x < 32) ts[threadIdx.x] = t[k0 + threadIdx.x];
    __syncthreads();
    float acc = (kc == 0) ? b3[o] : 0.f;
    #pragma unroll 8
    for (int k = 0; k < 32; k++) acc = fmaf(ts[k], W3[(size_t)(k0 + k) * 1024 + o], acc);
    atomicAdd(&g[o], acc);
}

// ---------- K7: head layer-1 partial matvecs (bias/relu deferred) ----------
__global__ __launch_bounds__(256) void k_heads1(const float* __restrict__ g,
                                                const float* __restrict__ Wv1,
                                                const float* __restrict__ Wa1,
                                                float* __restrict__ hv_raw,
                                                float* __restrict__ ha_raw) {
    int b = blockIdx.x;
    int oc = b >> 4, kc = b & 15;
    int idx = oc * 256 + threadIdx.x;  // 0..4095
    int k0 = kc * 64;
    __shared__ float gs[64];
    if (threadIdx.x < 64) gs[threadIdx.x] = g[k0 + threadIdx.x];
    __syncthreads();
    const float* W; float* outp; int o;
    if (idx < 2048) { W = Wv1; outp = hv_raw; o = idx; }
    else            { W = Wa1; outp = ha_raw; o = idx - 2048; }
    float acc = 0.f;
    #pragma unroll 8
    for (int k = 0; k < 64; k++) acc = fmaf(gs[k], W[(size_t)(k0 + k) * 2048 + o], acc);
    atomicAdd(&outp[o], acc);
}

// ---------- K8: head layer-2 + fused final (exit-style lastFlag; no spinning) ----------
__global__ __launch_bounds__(256) void k_heads2f(const float* __restrict__ hv_raw,
                                                 const float* __restrict__ bv1,
                                                 const float* __restrict__ ha_raw,
                                                 const float* __restrict__ ba1,
                                                 const float* __restrict__ Wv2,
                                                 const float* __restrict__ bv2,
                                                 const float* __restrict__ Wa2,
                                                 const float* __restrict__ ba2,
                                                 float* __restrict__ a_acc,
                                                 float* __restrict__ v,
                                                 int* __restrict__ done,
                                                 float* __restrict__ out) {
    __shared__ float sh[256];
    __shared__ int lastFlag;
    int b = blockIdx.x;
    int tid = threadIdx.x;
    if (b < 128) {
        int oc = b >> 5, kc = b & 31;   // oc 0..3, kc 0..31
        int k0 = kc * 64;
        if (tid < 64) sh[tid] = fmaxf(ha_raw[k0 + tid] + ba1[k0 + tid], 0.f);
        __syncthreads();
        int o = oc * 256 + tid;  // 0..1023
        if (o < 1000) {
            float acc = 0.f;
            #pragma unroll 8
            for (int k = 0; k < 64; k++)
                acc = fmaf(sh[k], Wa2[(size_t)(k0 + k) * 1000 + o], acc);
            atomicAdd(&a_acc[o], acc);
        }
    } else {
        float acc = 0.f;
        for (int k = tid; k < 2048; k += 256)
            acc = fmaf(fmaxf(hv_raw[k] + bv1[k], 0.f), Wv2[k], acc);
        sh[tid] = acc;
        __syncthreads();
        for (int s2 = 128; s2 >= 1; s2 >>= 1) {
            if (tid < s2) sh[tid] += sh[tid + s2];
            __syncthreads();
        }
        if (tid == 0) *v = sh[0] + bv2[0];
    }
    __syncthreads();
    if (tid == 0) {
        __threadfence();
        int old = atomicAdd(done, 1);
        lastFlag = (old == 128) ? 1 : 0;
    }
    __syncthreads();
    if (!lastFlag) return;
    __threadfence();
    float ai[4];
    float lsum = 0.f;
    #pragma unroll
    for (int k = 0; k < 4; k++) {
        int idx = tid + k * 256;
        float val = (idx < 1000) ? a_acc[idx] + ba2[idx] : 0.f;
        ai[k] = val;
        lsum += val;
    }
    __syncthreads();
    sh[tid] = lsum;
    __syncthreads();
    for (int s2 = 128; s2 >= 1; s2 >>= 1) {
        if (tid < s2) sh[tid] += sh[tid + s2];
        __syncthreads();
    }
    float amean = sh[0] * (1.0f / 1000.0f);
    float vv = *v;
    #pragma unroll
    for (int k = 0; k < 4; k++) {
        int idx = tid + k * 256;
        if (idx < 1000) out[idx] = vv + ai[k] - amean;
    }
}

extern "C" void kernel_launch(void* const* d_in, const int* in_sizes, int n_in,
                              void* d_out, int out_size, void* d_ws, size_t ws_size,
                              hipStream_t stream) {
    const float* x   = (const float*)d_in[0];
    const float* ef  = (const float*)d_in[1];
    const float* W1  = (const float*)d_in[2];
    const float* b1  = (const float*)d_in[3];
    const float* W2  = (const float*)d_in[4];
    const float* b2  = (const float*)d_in[5];
    const float* W3  = (const float*)d_in[6];
    const float* b3  = (const float*)d_in[7];
    const float* Wv1 = (const float*)d_in[8];
    const float* bv1 = (const float*)d_in[9];
    const float* Wv2 = (const float*)d_in[10];
    const float* bv2 = (const float*)d_in[11];
    const float* Wa1 = (const float*)d_in[12];
    const float* ba1 = (const float*)d_in[13];
    const float* Wa2 = (const float*)d_in[14];
    const float* ba2 = (const float*)d_in[15];
    const int*   src = (const int*)d_in[16];
    const int*   dst = (const int*)d_in[17];
    float* out = (float*)d_out;

    char* ws = (char*)d_ws;
    size_t off = 0;
    auto alloc = [&](size_t bytes) -> void* {
        void* p = ws + off;
        off = (off + bytes + 255) & ~(size_t)255;
        return p;
    };
    // --- zeroed region (counters + accumulators) ---
    int*   cnt_in  = (int*)  alloc(NN * 4);
    int*   cnt_out = (int*)  alloc(NN * 4);
    float* t       = (float*)alloc(512 * 4);
    float* g       = (float*)alloc(1024 * 4);
    float* hv_raw  = (float*)alloc(2048 * 4);
    float* ha_raw  = (float*)alloc(2048 * 4);
    float* a_acc   = (float*)alloc(1024 * 4);
    int*   done    = (int*)  alloc(256);
    size_t zero_bytes = off;
    // --- non-zeroed scratch ---
    int2*  pbuck   = (int2*) alloc((size_t)NN * CAP * 8);
    int*   obuck   = (int*)  alloc((size_t)NN * CAP * 4);
    float* din_arr = (float*)alloc(NN * 4);
    float4* dsx4   = (float4*)alloc((size_t)NN * 16);
    float* c       = (float*)alloc(NN * 4);
    float* h1s     = (float*)alloc((size_t)NN * 11 * 4);
    float* agg2    = (float*)alloc((size_t)NN * 11 * 4);
    float* v       = (float*)alloc(256);

    hipMemsetAsync(d_ws, 0, zero_bytes, stream);

    k_scat<<<(NE + 255) / 256, 256, 0, stream>>>(src, dst, cnt_in, cnt_out, pbuck, obuck);
    k_node<<<(NN + 255) / 256, 256, 0, stream>>>(x, cnt_in, cnt_out, din_arr, dsx4);
    // DIAGNOSTIC: k_conv1c and k_agg2 are pure functions of their inputs
    // (idempotent). Launch each 3x: dur_us inflation = 2*(conv1c + agg2) + 4 gaps.
    // Output must be bitwise identical (absmax must repeat 1.490116e-08).
    for (int rep = 0; rep < 3; rep++)
        k_conv1c<<<(NN + 63) / 64, 256, 0, stream>>>(cnt_in, cnt_out, pbuck, obuck,
                                                     din_arr, dsx4, W1, b1, h1s, c);
    for (int rep = 0; rep < 3; rep++)
        k_agg2<<<(NN + 22) / 23, 256, 0, stream>>>(cnt_in, pbuck, h1s, ef, agg2);
    k_conv2_reduce<<<(NN + NPB - 1) / NPB, 512, 0, stream>>>(agg2, W2, b2, c,
                                                             cnt_out, cnt_in, t);
    k_g<<<64, 256, 0, stream>>>(t, W3, b3, g);
    k_heads1<<<256, 256, 0, stream>>>(g, Wv1, Wa1, hv_raw, ha_raw);
    k_heads2f<<<129, 256, 0, stream>>>(hv_raw, bv1, ha_raw, ba1, Wv2, bv2, Wa2, ba2,
                                       a_acc, v, done, out);
}